// Round 2
// baseline (2320.748 us; speedup 1.0000x reference)
//
#include <hip/hip_runtime.h>
#include <math.h>

// 3-layer LSTM (H=64, D=300, B=256, T=512) + MLP head (64 -> tanh 64 -> 300).
// Runtime dtype dispatch (bf16 vs fp32) decided on-device; internal compute fp32.
// Time-chunked (TC=128) so ws stays ~59MB.

#define TT 512
#define BB 256
#define DD 300
#define HH 64
#define MM (TT * BB)
#define XP 256            // 4H
#define TC 128            // time chunk
#define NC (TT / TC)

__device__ __forceinline__ float bf2f(unsigned short u) {
    return __uint_as_float(((unsigned int)u) << 16);
}
__device__ __forceinline__ unsigned short f2bf(float f) {
    unsigned int x = __float_as_uint(f);
    x += 0x7FFFu + ((x >> 16) & 1u);   // RNE
    return (unsigned short)(x >> 16);
}
__device__ __forceinline__ float sigm(float x) { return 1.f / (1.f + __expf(-x)); }
__device__ __forceinline__ float tanh_f(float x) { return 1.f - 2.f / (__expf(2.f * x) + 1.f); }

// dual-mode loads: md==1 -> fp32 buffer, md==0 -> bf16 buffer
__device__ __forceinline__ float ld1(const void* p, long long i, int md) {
    return md ? ((const float*)p)[i] : bf2f(((const unsigned short*)p)[i]);
}
__device__ __forceinline__ void ld4v(float* d, const void* p, long long i, int md) {
    if (md) {
        float4 v = *(const float4*)((const float*)p + i);
        d[0] = v.x; d[1] = v.y; d[2] = v.z; d[3] = v.w;
    } else {
        ushort4 u = *(const ushort4*)((const unsigned short*)p + i);
        d[0] = bf2f(u.x); d[1] = bf2f(u.y); d[2] = bf2f(u.z); d[3] = bf2f(u.w);
    }
}

#define FMA4x4(a, bv)                                        \
    acc[0][0] = fmaf((a).x, (bv).x, acc[0][0]);              \
    acc[0][1] = fmaf((a).x, (bv).y, acc[0][1]);              \
    acc[0][2] = fmaf((a).x, (bv).z, acc[0][2]);              \
    acc[0][3] = fmaf((a).x, (bv).w, acc[0][3]);              \
    acc[1][0] = fmaf((a).y, (bv).x, acc[1][0]);              \
    acc[1][1] = fmaf((a).y, (bv).y, acc[1][1]);              \
    acc[1][2] = fmaf((a).y, (bv).z, acc[1][2]);              \
    acc[1][3] = fmaf((a).y, (bv).w, acc[1][3]);              \
    acc[2][0] = fmaf((a).z, (bv).x, acc[2][0]);              \
    acc[2][1] = fmaf((a).z, (bv).y, acc[2][1]);              \
    acc[2][2] = fmaf((a).z, (bv).z, acc[2][2]);              \
    acc[2][3] = fmaf((a).z, (bv).w, acc[2][3]);              \
    acc[3][0] = fmaf((a).w, (bv).x, acc[3][0]);              \
    acc[3][1] = fmaf((a).w, (bv).y, acc[3][1]);              \
    acc[3][2] = fmaf((a).w, (bv).z, acc[3][2]);              \
    acc[3][3] = fmaf((a).w, (bv).w, acc[3][3]);

// ---------------------------------------------------------------------------
// detect dtype: bf16-decode first 256 halfwords; fp32 data -> many insane.
// ---------------------------------------------------------------------------
__global__ void detect_kernel(const void* inp, int* mode) {
    if (threadIdx.x == 0 && blockIdx.x == 0) {
        const unsigned short* u = (const unsigned short*)inp;
        int bad = 0;
        for (int i = 0; i < 256; ++i) {
            float f = bf2f(u[i]);
            if (!(f == f) || fabsf(f) > 1e6f) ++bad;
        }
        *mode = (bad >= 4) ? 1 : 0;
    }
}

__global__ __launch_bounds__(256) void init_state(
    const void* h0, const void* c0, float* hstate, float* cstate, const int* modep)
{
    const int md = *modep;
    int i = blockIdx.x * 256 + threadIdx.x;
    if (i < 3 * BB * HH) {
        hstate[i] = ld1(h0, i, md);
        cstate[i] = ld1(c0, i, md);
    }
}

__global__ __launch_bounds__(256) void final_state(
    const float* hstate, const float* cstate, void* out, const int* modep)
{
    const int md = *modep;
    int i = blockIdx.x * 256 + threadIdx.x;
    const long long base = (long long)MM * DD;
    if (i < 3 * BB * HH) {
        if (md) {
            ((float*)out)[base + i] = hstate[i];
            ((float*)out)[base + 3 * BB * HH + i] = cstate[i];
        } else {
            ((unsigned short*)out)[base + i] = f2bf(hstate[i]);
            ((unsigned short*)out)[base + 3 * BB * HH + i] = f2bf(cstate[i]);
        }
    }
}

// ---------------------------------------------------------------------------
// proj0_chunk: xp[ml][n] = sum_k input(b,t,k)*wih0[n][k] + bih0[n]+bhh0[n]
// ml = t_local*256+b (chunk-local), t = chunk*TC + t_local. grid (512,4), blk 256
// ---------------------------------------------------------------------------
__global__ __launch_bounds__(256) void proj0_chunk(
    const void* __restrict__ inp, const void* __restrict__ wih,
    const void* __restrict__ bih, const void* __restrict__ bhh,
    float* __restrict__ xp, const int* modep, int chunk)
{
    const int md = *modep;
    __shared__ __align__(16) float At[64][68];
    __shared__ __align__(16) float Wt[64][68];
    const int tid = threadIdx.x;
    const int lr = tid >> 2;
    const int lc = (tid & 3) * 16;
    const int tx = tid & 15, ty = tid >> 4;
    const int m0 = blockIdx.x * 64, n0 = blockIdx.y * 64;
    const int ml = m0 + lr;
    const int b = ml & 255;
    const int t = chunk * TC + (ml >> 8);
    const long long abase = (long long)b * (TT * DD) + (long long)t * DD;
    const long long wbase = (long long)(n0 + lr) * DD;
    float acc[4][4] = {{0.f,0.f,0.f,0.f},{0.f,0.f,0.f,0.f},{0.f,0.f,0.f,0.f},{0.f,0.f,0.f,0.f}};
    for (int k0 = 0; k0 < DD; k0 += 64) {
        if (k0 + lc + 15 < DD) {
            #pragma unroll
            for (int q = 0; q < 4; ++q) {
                float va[4], vw[4];
                ld4v(va, inp, abase + k0 + lc + q * 4, md);
                ld4v(vw, wih, wbase + k0 + lc + q * 4, md);
                #pragma unroll
                for (int e = 0; e < 4; ++e) {
                    At[lc + q * 4 + e][lr] = va[e];
                    Wt[lc + q * 4 + e][lr] = vw[e];
                }
            }
        } else {
            #pragma unroll
            for (int q = 0; q < 16; ++q) {
                int k = k0 + lc + q;
                At[lc + q][lr] = (k < DD) ? ld1(inp, abase + k, md) : 0.f;
                Wt[lc + q][lr] = (k < DD) ? ld1(wih, wbase + k, md) : 0.f;
            }
        }
        __syncthreads();
        #pragma unroll 16
        for (int k = 0; k < 64; ++k) {
            float4 a = *(const float4*)&At[k][ty * 4];
            float4 bv = *(const float4*)&Wt[k][tx * 4];
            FMA4x4(a, bv)
        }
        __syncthreads();
    }
    float bias[4];
    #pragma unroll
    for (int j = 0; j < 4; ++j) {
        int n = n0 + tx * 4 + j;
        bias[j] = ld1(bih, n, md) + ld1(bhh, n, md);
    }
    #pragma unroll
    for (int i = 0; i < 4; ++i) {
        long long row = m0 + ty * 4 + i;
        float4 o = make_float4(acc[i][0] + bias[0], acc[i][1] + bias[1],
                               acc[i][2] + bias[2], acc[i][3] + bias[3]);
        *(float4*)(xp + row * XP + n0 + tx * 4) = o;
    }
}

// ---------------------------------------------------------------------------
// scan0_chunk: layer 0 recurrence over TC steps. 1 block per batch row.
// xp has bias folded. State in/out fp32 ws.
// ---------------------------------------------------------------------------
__global__ __launch_bounds__(256) void scan0_chunk(
    const float* __restrict__ xp, float* __restrict__ hs,
    const void* __restrict__ whh,
    float* __restrict__ hstate, float* __restrict__ cstate, const int* modep)
{
    const int md = *modep;
    const int b = blockIdx.x;
    const int j = threadIdx.x;
    __shared__ __align__(16) float h_s[64];
    __shared__ float g_s[256];
    float w[64];
    #pragma unroll
    for (int q = 0; q < 16; ++q) {
        float v[4];
        ld4v(v, whh, (long long)j * HH + q * 4, md);
        w[q*4+0]=v[0]; w[q*4+1]=v[1]; w[q*4+2]=v[2]; w[q*4+3]=v[3];
    }
    float c = 0.f;
    if (j < 64) {
        h_s[j] = hstate[b * HH + j];
        c = cstate[b * HH + j];
    }
    __syncthreads();
    const float4* h4 = (const float4*)h_s;
    const long long xbase = (long long)b * XP + j;
    float xv = xp[xbase];
    for (int t = 0; t < TC; ++t) {
        float xnext = (t < TC - 1) ? xp[xbase + (long long)(t + 1) * (BB * XP)] : 0.f;
        float a0 = xv, a1 = 0.f, a2 = 0.f, a3 = 0.f;
        #pragma unroll
        for (int q = 0; q < 16; ++q) {
            float4 hv = h4[q];
            a0 = fmaf(hv.x, w[4*q+0], a0);
            a1 = fmaf(hv.y, w[4*q+1], a1);
            a2 = fmaf(hv.z, w[4*q+2], a2);
            a3 = fmaf(hv.w, w[4*q+3], a3);
        }
        g_s[j] = (a0 + a1) + (a2 + a3);
        __syncthreads();
        if (j < 64) {
            float gi = g_s[j], gf = g_s[64+j], gg = g_s[128+j], go = g_s[192+j];
            c = sigm(gf) * c + sigm(gi) * tanh_f(gg);
            float h = sigm(go) * tanh_f(c);
            h_s[j] = h;
            hs[((long long)t * BB + b) * HH + j] = h;
        }
        __syncthreads();
        xv = xnext;
    }
    if (j < 64) {
        hstate[b * HH + j] = h_s[j];
        cstate[b * HH + j] = c;
    }
}

// ---------------------------------------------------------------------------
// scanh_chunk: hidden layer; input projection fused (wih in registers).
// x_s double-buffered in LDS (threads 64..127 prefetch next x row).
// ---------------------------------------------------------------------------
__global__ __launch_bounds__(256) void scanh_chunk(
    const float* __restrict__ hsprev, float* __restrict__ hs,
    const void* __restrict__ wih, const void* __restrict__ whh,
    const void* __restrict__ bih, const void* __restrict__ bhh,
    float* __restrict__ hstate, float* __restrict__ cstate, const int* modep)
{
    const int md = *modep;
    const int b = blockIdx.x;
    const int j = threadIdx.x;
    __shared__ __align__(16) float h_s[64];
    __shared__ __align__(16) float x_s[2][64];
    __shared__ float g_s[256];
    float wi[64], wh[64];
    #pragma unroll
    for (int q = 0; q < 16; ++q) {
        float vi[4], vh[4];
        ld4v(vi, wih, (long long)j * HH + q * 4, md);
        ld4v(vh, whh, (long long)j * HH + q * 4, md);
        #pragma unroll
        for (int e = 0; e < 4; ++e) { wi[q*4+e]=vi[e]; wh[q*4+e]=vh[e]; }
    }
    const float bj = ld1(bih, j, md) + ld1(bhh, j, md);
    float c = 0.f;
    if (j < 64) {
        h_s[j] = hstate[b * HH + j];
        c = cstate[b * HH + j];
    } else if (j < 128) {
        x_s[0][j - 64] = hsprev[(long long)b * HH + (j - 64)];
    }
    __syncthreads();
    const float4* h4 = (const float4*)h_s;
    for (int t = 0; t < TC; ++t) {
        const float4* x4 = (const float4*)x_s[t & 1];
        float a0 = bj, a1 = 0.f, a2 = 0.f, a3 = 0.f;
        #pragma unroll
        for (int q = 0; q < 16; ++q) {
            float4 hv = h4[q];
            float4 xv = x4[q];
            a0 = fmaf(hv.x, wh[4*q+0], a0);
            a1 = fmaf(hv.y, wh[4*q+1], a1);
            a2 = fmaf(hv.z, wh[4*q+2], a2);
            a3 = fmaf(hv.w, wh[4*q+3], a3);
            a0 = fmaf(xv.x, wi[4*q+0], a0);
            a1 = fmaf(xv.y, wi[4*q+1], a1);
            a2 = fmaf(xv.z, wi[4*q+2], a2);
            a3 = fmaf(xv.w, wi[4*q+3], a3);
        }
        g_s[j] = (a0 + a1) + (a2 + a3);
        __syncthreads();
        if (j < 64) {
            float gi = g_s[j], gf = g_s[64+j], gg = g_s[128+j], go = g_s[192+j];
            c = sigm(gf) * c + sigm(gi) * tanh_f(gg);
            float h = sigm(go) * tanh_f(c);
            h_s[j] = h;
            hs[((long long)t * BB + b) * HH + j] = h;
        } else if (j < 128 && t + 1 < TC) {
            x_s[(t + 1) & 1][j - 64] = hsprev[((long long)(t + 1) * BB + b) * HH + (j - 64)];
        }
        __syncthreads();
    }
    if (j < 64) {
        hstate[b * HH + j] = h_s[j];
        cstate[b * HH + j] = c;
    }
}

// ---------------------------------------------------------------------------
// head_chunk: y = tanh(hs2 @ w1^T + b1) @ w2^T + b2 for one time chunk.
// LDS: Ht, Wt (w1 then w2 tiles), Zt -> 52KB.
// ---------------------------------------------------------------------------
__global__ __launch_bounds__(256) void head_chunk(
    const float* __restrict__ hs, const void* __restrict__ w1,
    const void* __restrict__ b1, const void* __restrict__ w2,
    const void* __restrict__ b2, void* __restrict__ out,
    const int* modep, int chunk)
{
    const int md = *modep;
    __shared__ __align__(16) float Ht[64][68];
    __shared__ __align__(16) float Wt[64][68];
    __shared__ __align__(16) float Zt[64][68];
    const int tid = threadIdx.x;
    const int lr = tid >> 2;
    const int lc = (tid & 3) * 16;
    const int tx = tid & 15, ty = tid >> 4;
    const int m0 = blockIdx.x * 64;                       // chunk-local row tile
    const long long gbase = (long long)chunk * TC * BB;   // global row offset
    #pragma unroll
    for (int q = 0; q < 4; ++q) {
        float4 av = *(const float4*)(hs + (long long)(m0 + lr) * HH + lc + q * 4);
        float vw[4];
        ld4v(vw, w1, (long long)lr * HH + lc + q * 4, md);
        Ht[lc+q*4+0][lr]=av.x; Ht[lc+q*4+1][lr]=av.y; Ht[lc+q*4+2][lr]=av.z; Ht[lc+q*4+3][lr]=av.w;
        Wt[lc+q*4+0][lr]=vw[0]; Wt[lc+q*4+1][lr]=vw[1]; Wt[lc+q*4+2][lr]=vw[2]; Wt[lc+q*4+3][lr]=vw[3];
    }
    __syncthreads();
    {
        float acc[4][4] = {{0.f,0.f,0.f,0.f},{0.f,0.f,0.f,0.f},{0.f,0.f,0.f,0.f},{0.f,0.f,0.f,0.f}};
        #pragma unroll 16
        for (int k = 0; k < 64; ++k) {
            float4 a = *(const float4*)&Ht[k][ty * 4];
            float4 bv = *(const float4*)&Wt[k][tx * 4];
            FMA4x4(a, bv)
        }
        #pragma unroll
        for (int jj = 0; jj < 4; ++jj) {
            float bb = ld1(b1, tx * 4 + jj, md);
            #pragma unroll
            for (int ii = 0; ii < 4; ++ii)
                Zt[tx * 4 + jj][ty * 4 + ii] = tanh_f(acc[ii][jj] + bb);
        }
    }
    __syncthreads();   // MAC1 + Zt complete; Wt free for reuse
    for (int dt = 0; dt < 5; ++dt) {
        const int d0 = dt * 64;
        if (d0 + lr < DD) {
            #pragma unroll
            for (int q = 0; q < 4; ++q) {
                float vw[4];
                ld4v(vw, w2, (long long)(d0 + lr) * HH + lc + q * 4, md);
                Wt[lc+q*4+0][lr]=vw[0]; Wt[lc+q*4+1][lr]=vw[1];
                Wt[lc+q*4+2][lr]=vw[2]; Wt[lc+q*4+3][lr]=vw[3];
            }
        }
        __syncthreads();
        float acc[4][4] = {{0.f,0.f,0.f,0.f},{0.f,0.f,0.f,0.f},{0.f,0.f,0.f,0.f},{0.f,0.f,0.f,0.f}};
        #pragma unroll 16
        for (int k = 0; k < 64; ++k) {
            float4 a = *(const float4*)&Zt[k][ty * 4];
            float4 bv = *(const float4*)&Wt[k][tx * 4];
            FMA4x4(a, bv)
        }
        const int d = d0 + tx * 4;
        if (d < DD) {   // 300 % 4 == 0
            float bb0 = ld1(b2, d + 0, md), bb1 = ld1(b2, d + 1, md);
            float bb2v = ld1(b2, d + 2, md), bb3 = ld1(b2, d + 3, md);
            #pragma unroll
            for (int ii = 0; ii < 4; ++ii) {
                long long row = gbase + m0 + ty * 4 + ii;
                float o0 = acc[ii][0] + bb0, o1 = acc[ii][1] + bb1;
                float o2 = acc[ii][2] + bb2v, o3 = acc[ii][3] + bb3;
                if (md) {
                    *(float4*)((float*)out + row * DD + d) = make_float4(o0, o1, o2, o3);
                } else {
                    ushort4 o;
                    o.x = f2bf(o0); o.y = f2bf(o1); o.z = f2bf(o2); o.w = f2bf(o3);
                    *(ushort4*)((unsigned short*)out + row * DD + d) = o;
                }
            }
        }
        __syncthreads();
    }
}

// ---------------------------------------------------------------------------
extern "C" void kernel_launch(void* const* d_in, const int* in_sizes, int n_in,
                              void* d_out, int out_size, void* d_ws, size_t ws_size,
                              hipStream_t stream)
{
    const void* inp  = d_in[0];
    const void* h0   = d_in[1];
    const void* c0   = d_in[2];
    const void* wih0 = d_in[3];
    const void* whh0 = d_in[4];
    const void* bih0 = d_in[5];
    const void* bhh0 = d_in[6];
    const void* wih1 = d_in[7];
    const void* whh1 = d_in[8];
    const void* bih1 = d_in[9];
    const void* bhh1 = d_in[10];
    const void* wih2 = d_in[11];
    const void* whh2 = d_in[12];
    const void* bih2 = d_in[13];
    const void* bhh2 = d_in[14];
    const void* w1   = d_in[15];
    const void* b1   = d_in[16];
    const void* w2   = d_in[17];
    const void* b2   = d_in[18];

    int* mode = (int*)d_ws;
    float* wsf = (float*)d_ws;
    float* hstate = wsf + 16;                          // [3,256,64]
    float* cstate = hstate + 3 * BB * HH;
    float* xp  = cstate + 3 * BB * HH;                 // [TC*256, 256]
    float* hs0 = xp + (size_t)TC * BB * XP;            // [TC*256, 64]
    float* hs1 = hs0 + (size_t)TC * BB * HH;
    float* hs2 = hs1 + (size_t)TC * BB * HH;
    // total ~59.1 MB

    detect_kernel<<<1, 64, 0, stream>>>(inp, mode);
    init_state<<<192, 256, 0, stream>>>(h0, c0, hstate, cstate, mode);

    for (int c = 0; c < NC; ++c) {
        proj0_chunk<<<dim3(TC * BB / 64, 4), 256, 0, stream>>>(
            inp, wih0, bih0, bhh0, xp, mode, c);
        scan0_chunk<<<BB, 256, 0, stream>>>(
            xp, hs0, whh0, hstate, cstate, mode);
        scanh_chunk<<<BB, 256, 0, stream>>>(
            hs0, hs1, wih1, whh1, bih1, bhh1,
            hstate + BB * HH, cstate + BB * HH, mode);
        scanh_chunk<<<BB, 256, 0, stream>>>(
            hs1, hs2, wih2, whh2, bih2, bhh2,
            hstate + 2 * BB * HH, cstate + 2 * BB * HH, mode);
        head_chunk<<<TC * BB / 64, 256, 0, stream>>>(
            hs2, w1, b1, w2, b2, d_out, mode, c);
    }
    final_state<<<192, 256, 0, stream>>>(hstate, cstate, d_out, mode);
}

// Round 3
// 1918.486 us; speedup vs baseline: 1.2097x; 1.2097x over previous
//
#include <hip/hip_runtime.h>
#include <math.h>

// 3-layer LSTM (H=64, D=300, B=256, T=512) + MLP head (64 -> tanh 64 -> 300).
// Runtime dtype dispatch (bf16 vs fp32) decided on-device; internal compute fp32.
// Time-chunked (TC=128), ws ~59MB.
// R3: scans restructured — input projections unfused (parallel GEMM for all
// layers), x register-prefetched, 1 raw s_barrier/step (lgkmcnt-only wait),
// per-gate nonlinearity pre-barrier, redundant per-wave h/c update.

#define TT 512
#define BB 256
#define DD 300
#define HH 64
#define MM (TT * BB)
#define XP 256            // 4H
#define TC 128            // time chunk
#define NC (TT / TC)

__device__ __forceinline__ float bf2f(unsigned short u) {
    return __uint_as_float(((unsigned int)u) << 16);
}
__device__ __forceinline__ unsigned short f2bf(float f) {
    unsigned int x = __float_as_uint(f);
    x += 0x7FFFu + ((x >> 16) & 1u);   // RNE
    return (unsigned short)(x >> 16);
}
__device__ __forceinline__ float sigm(float x) { return 1.f / (1.f + __expf(-x)); }
__device__ __forceinline__ float tanh_f(float x) { return 1.f - 2.f / (__expf(2.f * x) + 1.f); }

// dual-mode loads: md==1 -> fp32 buffer, md==0 -> bf16 buffer
__device__ __forceinline__ float ld1(const void* p, long long i, int md) {
    return md ? ((const float*)p)[i] : bf2f(((const unsigned short*)p)[i]);
}
__device__ __forceinline__ void ld4v(float* d, const void* p, long long i, int md) {
    if (md) {
        float4 v = *(const float4*)((const float*)p + i);
        d[0] = v.x; d[1] = v.y; d[2] = v.z; d[3] = v.w;
    } else {
        ushort4 u = *(const ushort4*)((const unsigned short*)p + i);
        d[0] = bf2f(u.x); d[1] = bf2f(u.y); d[2] = bf2f(u.z); d[3] = bf2f(u.w);
    }
}

#define FMA4x4(a, bv)                                        \
    acc[0][0] = fmaf((a).x, (bv).x, acc[0][0]);              \
    acc[0][1] = fmaf((a).x, (bv).y, acc[0][1]);              \
    acc[0][2] = fmaf((a).x, (bv).z, acc[0][2]);              \
    acc[0][3] = fmaf((a).x, (bv).w, acc[0][3]);              \
    acc[1][0] = fmaf((a).y, (bv).x, acc[1][0]);              \
    acc[1][1] = fmaf((a).y, (bv).y, acc[1][1]);              \
    acc[1][2] = fmaf((a).y, (bv).z, acc[1][2]);              \
    acc[1][3] = fmaf((a).y, (bv).w, acc[1][3]);              \
    acc[2][0] = fmaf((a).z, (bv).x, acc[2][0]);              \
    acc[2][1] = fmaf((a).z, (bv).y, acc[2][1]);              \
    acc[2][2] = fmaf((a).z, (bv).z, acc[2][2]);              \
    acc[2][3] = fmaf((a).z, (bv).w, acc[2][3]);              \
    acc[3][0] = fmaf((a).w, (bv).x, acc[3][0]);              \
    acc[3][1] = fmaf((a).w, (bv).y, acc[3][1]);              \
    acc[3][2] = fmaf((a).w, (bv).z, acc[3][2]);              \
    acc[3][3] = fmaf((a).w, (bv).w, acc[3][3]);

// ---------------------------------------------------------------------------
__global__ void detect_kernel(const void* inp, int* mode) {
    if (threadIdx.x == 0 && blockIdx.x == 0) {
        const unsigned short* u = (const unsigned short*)inp;
        int bad = 0;
        for (int i = 0; i < 256; ++i) {
            float f = bf2f(u[i]);
            if (!(f == f) || fabsf(f) > 1e6f) ++bad;
        }
        *mode = (bad >= 4) ? 1 : 0;
    }
}

__global__ __launch_bounds__(256) void init_state(
    const void* h0, const void* c0, float* hstate, float* cstate, const int* modep)
{
    const int md = *modep;
    int i = blockIdx.x * 256 + threadIdx.x;
    if (i < 3 * BB * HH) {
        hstate[i] = ld1(h0, i, md);
        cstate[i] = ld1(c0, i, md);
    }
}

__global__ __launch_bounds__(256) void final_state(
    const float* hstate, const float* cstate, void* out, const int* modep)
{
    const int md = *modep;
    int i = blockIdx.x * 256 + threadIdx.x;
    const long long base = (long long)MM * DD;
    if (i < 3 * BB * HH) {
        if (md) {
            ((float*)out)[base + i] = hstate[i];
            ((float*)out)[base + 3 * BB * HH + i] = cstate[i];
        } else {
            ((unsigned short*)out)[base + i] = f2bf(hstate[i]);
            ((unsigned short*)out)[base + 3 * BB * HH + i] = f2bf(cstate[i]);
        }
    }
}

// ---------------------------------------------------------------------------
// proj0_chunk: xp[ml][n] = sum_k input(b,t,k)*wih0[n][k] + bih0[n]+bhh0[n]
// ml = t_local*256+b, t = chunk*TC + t_local. grid (512,4), blk 256
// ---------------------------------------------------------------------------
__global__ __launch_bounds__(256) void proj0_chunk(
    const void* __restrict__ inp, const void* __restrict__ wih,
    const void* __restrict__ bih, const void* __restrict__ bhh,
    float* __restrict__ xp, const int* modep, int chunk)
{
    const int md = *modep;
    __shared__ __align__(16) float At[64][68];
    __shared__ __align__(16) float Wt[64][68];
    const int tid = threadIdx.x;
    const int lr = tid >> 2;
    const int lc = (tid & 3) * 16;
    const int tx = tid & 15, ty = tid >> 4;
    const int m0 = blockIdx.x * 64, n0 = blockIdx.y * 64;
    const int ml = m0 + lr;
    const int b = ml & 255;
    const int t = chunk * TC + (ml >> 8);
    const long long abase = (long long)b * (TT * DD) + (long long)t * DD;
    const long long wbase = (long long)(n0 + lr) * DD;
    float acc[4][4] = {{0.f,0.f,0.f,0.f},{0.f,0.f,0.f,0.f},{0.f,0.f,0.f,0.f},{0.f,0.f,0.f,0.f}};
    for (int k0 = 0; k0 < DD; k0 += 64) {
        if (k0 + lc + 15 < DD) {
            #pragma unroll
            for (int q = 0; q < 4; ++q) {
                float va[4], vw[4];
                ld4v(va, inp, abase + k0 + lc + q * 4, md);
                ld4v(vw, wih, wbase + k0 + lc + q * 4, md);
                #pragma unroll
                for (int e = 0; e < 4; ++e) {
                    At[lc + q * 4 + e][lr] = va[e];
                    Wt[lc + q * 4 + e][lr] = vw[e];
                }
            }
        } else {
            #pragma unroll
            for (int q = 0; q < 16; ++q) {
                int k = k0 + lc + q;
                At[lc + q][lr] = (k < DD) ? ld1(inp, abase + k, md) : 0.f;
                Wt[lc + q][lr] = (k < DD) ? ld1(wih, wbase + k, md) : 0.f;
            }
        }
        __syncthreads();
        #pragma unroll 16
        for (int k = 0; k < 64; ++k) {
            float4 a = *(const float4*)&At[k][ty * 4];
            float4 bv = *(const float4*)&Wt[k][tx * 4];
            FMA4x4(a, bv)
        }
        __syncthreads();
    }
    float bias[4];
    #pragma unroll
    for (int j = 0; j < 4; ++j) {
        int n = n0 + tx * 4 + j;
        bias[j] = ld1(bih, n, md) + ld1(bhh, n, md);
    }
    #pragma unroll
    for (int i = 0; i < 4; ++i) {
        long long row = m0 + ty * 4 + i;
        float4 o = make_float4(acc[i][0] + bias[0], acc[i][1] + bias[1],
                               acc[i][2] + bias[2], acc[i][3] + bias[3]);
        *(float4*)(xp + row * XP + n0 + tx * 4) = o;
    }
}

// ---------------------------------------------------------------------------
// projh_chunk: xp[m][n] = sum_k A[m][k]*wih[n][k] + bih[n]+bhh[n]
// A fp32 [TC*BB][64] (hs of previous layer). grid (512,4), blk 256
// ---------------------------------------------------------------------------
__global__ __launch_bounds__(256) void projh_chunk(
    const float* __restrict__ A, const void* __restrict__ wih,
    const void* __restrict__ bih, const void* __restrict__ bhh,
    float* __restrict__ xp, const int* modep)
{
    const int md = *modep;
    __shared__ __align__(16) float At[64][68];
    __shared__ __align__(16) float Wt[64][68];
    const int tid = threadIdx.x;
    const int lr = tid >> 2;
    const int lc = (tid & 3) * 16;
    const int tx = tid & 15, ty = tid >> 4;
    const int m0 = blockIdx.x * 64, n0 = blockIdx.y * 64;
    float acc[4][4] = {{0.f,0.f,0.f,0.f},{0.f,0.f,0.f,0.f},{0.f,0.f,0.f,0.f},{0.f,0.f,0.f,0.f}};
    #pragma unroll
    for (int q = 0; q < 4; ++q) {
        float4 av = *(const float4*)(A + (long long)(m0 + lr) * HH + lc + q * 4);
        float vw[4];
        ld4v(vw, wih, (long long)(n0 + lr) * HH + lc + q * 4, md);
        At[lc+q*4+0][lr]=av.x; At[lc+q*4+1][lr]=av.y; At[lc+q*4+2][lr]=av.z; At[lc+q*4+3][lr]=av.w;
        Wt[lc+q*4+0][lr]=vw[0]; Wt[lc+q*4+1][lr]=vw[1]; Wt[lc+q*4+2][lr]=vw[2]; Wt[lc+q*4+3][lr]=vw[3];
    }
    __syncthreads();
    #pragma unroll 16
    for (int k = 0; k < 64; ++k) {
        float4 a = *(const float4*)&At[k][ty * 4];
        float4 bv = *(const float4*)&Wt[k][tx * 4];
        FMA4x4(a, bv)
    }
    float bias[4];
    #pragma unroll
    for (int j = 0; j < 4; ++j) {
        int n = n0 + tx * 4 + j;
        bias[j] = ld1(bih, n, md) + ld1(bhh, n, md);
    }
    #pragma unroll
    for (int i = 0; i < 4; ++i) {
        long long row = m0 + ty * 4 + i;
        float4 o = make_float4(acc[i][0] + bias[0], acc[i][1] + bias[1],
                               acc[i][2] + bias[2], acc[i][3] + bias[3]);
        *(float4*)(xp + row * XP + n0 + tx * 4) = o;
    }
}

// ---------------------------------------------------------------------------
// scan_chunk: recurrence over TC steps, 1 block per batch row, 256 threads.
// Thread j computes gate type (j&3) of h-index (j>>2): gate g=(j&3)*64+(j>>2).
// Nonlinearity applied pre-barrier; gates stored so h-index m's {i,f,g,o} are
// contiguous (index j = 4*hidx+type). ONE raw s_barrier per step (lgkmcnt-only
// wait -> x prefetch loads and hs stores stay in flight). Every wave updates
// h/c redundantly (same-value LDS races are benign; g double-buffered by step
// parity bounds wave skew).
// ---------------------------------------------------------------------------
__global__ __launch_bounds__(256) void scan_chunk(
    const float* __restrict__ xp, float* __restrict__ hs,
    const void* __restrict__ whh,
    float* __restrict__ hstate, float* __restrict__ cstate, const int* modep)
{
    const int md = *modep;
    const int b = blockIdx.x;
    const int j = threadIdx.x;
    const int g = ((j & 3) << 6) | (j >> 2);   // gate row this thread computes
    const int m = j & 63;                      // h-index this thread updates
    __shared__ __align__(16) float h_s[64];
    __shared__ __align__(16) float g_s[2][256];
    float w[64];
    #pragma unroll
    for (int q = 0; q < 16; ++q) {
        float v[4];
        ld4v(v, whh, (long long)g * HH + q * 4, md);
        w[4*q+0]=v[0]; w[4*q+1]=v[1]; w[4*q+2]=v[2]; w[4*q+3]=v[3];
    }
    float c = cstate[b * HH + m];
    h_s[m] = hstate[b * HH + m];   // every wave writes all 64 (same values)
    float hval = h_s[m];

    const int type = j & 3;
    const float aa = (type == 2) ? 2.f : 1.f;  // tanh(x) = 2*sig(2x)-1
    const float cc = 1.f - aa;

    const long long xbase = (long long)b * XP + g;
    const long long xstep = (long long)BB * XP;
    float xc[8], xn[8];
    #pragma unroll
    for (int p = 0; p < 8; ++p) xc[p] = xp[xbase + (long long)p * xstep];

    for (int tg = 0; tg < TC; tg += 8) {
        if (tg + 8 < TC) {
            #pragma unroll
            for (int p = 0; p < 8; ++p)
                xn[p] = xp[xbase + (long long)(tg + 8 + p) * xstep];
        }
        #pragma unroll
        for (int u = 0; u < 8; ++u) {
            const int t = tg + u;
            // gate dot product: 4 independent fma chains of 16
            float a0 = xc[u], a1 = 0.f, a2 = 0.f, a3 = 0.f;
            const float4* h4 = (const float4*)h_s;
            #pragma unroll
            for (int q = 0; q < 16; ++q) {
                float4 hv = h4[q];
                a0 = fmaf(hv.x, w[4*q+0], a0);
                a1 = fmaf(hv.y, w[4*q+1], a1);
                a2 = fmaf(hv.z, w[4*q+2], a2);
                a3 = fmaf(hv.w, w[4*q+3], a3);
            }
            float gr = (a0 + a1) + (a2 + a3);
            // branchless nonlinearity: s=sig(aa*gr); y = aa*s + (1-aa)
            float s = 1.f / (1.f + __expf(-aa * gr));
            g_s[t & 1][j] = fmaf(aa, s, cc);
            // commit LDS writes, sync; NO vmcnt drain (prefetch stays in flight)
            asm volatile("s_waitcnt lgkmcnt(0)\n\ts_barrier" ::: "memory");
            float4 gv = *(const float4*)&g_s[t & 1][4 * m];  // {i,f,g,o} for m
            c = gv.y * c + gv.x * gv.z;
            hval = gv.w * tanh_f(c);
            h_s[m] = hval;
            if (j < 64) hs[((long long)t * BB + b) * HH + m] = hval;
        }
        #pragma unroll
        for (int p = 0; p < 8; ++p) xc[p] = xn[p];
    }
    if (j < 64) {
        hstate[b * HH + m] = hval;
        cstate[b * HH + m] = c;
    }
}

// ---------------------------------------------------------------------------
// head_chunk: y = tanh(hs2 @ w1^T + b1) @ w2^T + b2 for one time chunk.
// ---------------------------------------------------------------------------
__global__ __launch_bounds__(256) void head_chunk(
    const float* __restrict__ hs, const void* __restrict__ w1,
    const void* __restrict__ b1, const void* __restrict__ w2,
    const void* __restrict__ b2, void* __restrict__ out,
    const int* modep, int chunk)
{
    const int md = *modep;
    __shared__ __align__(16) float Ht[64][68];
    __shared__ __align__(16) float Wt[64][68];
    __shared__ __align__(16) float Zt[64][68];
    const int tid = threadIdx.x;
    const int lr = tid >> 2;
    const int lc = (tid & 3) * 16;
    const int tx = tid & 15, ty = tid >> 4;
    const int m0 = blockIdx.x * 64;
    const long long gbase = (long long)chunk * TC * BB;
    #pragma unroll
    for (int q = 0; q < 4; ++q) {
        float4 av = *(const float4*)(hs + (long long)(m0 + lr) * HH + lc + q * 4);
        float vw[4];
        ld4v(vw, w1, (long long)lr * HH + lc + q * 4, md);
        Ht[lc+q*4+0][lr]=av.x; Ht[lc+q*4+1][lr]=av.y; Ht[lc+q*4+2][lr]=av.z; Ht[lc+q*4+3][lr]=av.w;
        Wt[lc+q*4+0][lr]=vw[0]; Wt[lc+q*4+1][lr]=vw[1]; Wt[lc+q*4+2][lr]=vw[2]; Wt[lc+q*4+3][lr]=vw[3];
    }
    __syncthreads();
    {
        float acc[4][4] = {{0.f,0.f,0.f,0.f},{0.f,0.f,0.f,0.f},{0.f,0.f,0.f,0.f},{0.f,0.f,0.f,0.f}};
        #pragma unroll 16
        for (int k = 0; k < 64; ++k) {
            float4 a = *(const float4*)&Ht[k][ty * 4];
            float4 bv = *(const float4*)&Wt[k][tx * 4];
            FMA4x4(a, bv)
        }
        #pragma unroll
        for (int jj = 0; jj < 4; ++jj) {
            float bb = ld1(b1, tx * 4 + jj, md);
            #pragma unroll
            for (int ii = 0; ii < 4; ++ii)
                Zt[tx * 4 + jj][ty * 4 + ii] = tanh_f(acc[ii][jj] + bb);
        }
    }
    __syncthreads();
    for (int dt = 0; dt < 5; ++dt) {
        const int d0 = dt * 64;
        if (d0 + lr < DD) {
            #pragma unroll
            for (int q = 0; q < 4; ++q) {
                float vw[4];
                ld4v(vw, w2, (long long)(d0 + lr) * HH + lc + q * 4, md);
                Wt[lc+q*4+0][lr]=vw[0]; Wt[lc+q*4+1][lr]=vw[1];
                Wt[lc+q*4+2][lr]=vw[2]; Wt[lc+q*4+3][lr]=vw[3];
            }
        }
        __syncthreads();
        float acc[4][4] = {{0.f,0.f,0.f,0.f},{0.f,0.f,0.f,0.f},{0.f,0.f,0.f,0.f},{0.f,0.f,0.f,0.f}};
        #pragma unroll 16
        for (int k = 0; k < 64; ++k) {
            float4 a = *(const float4*)&Zt[k][ty * 4];
            float4 bv = *(const float4*)&Wt[k][tx * 4];
            FMA4x4(a, bv)
        }
        const int d = d0 + tx * 4;
        if (d < DD) {
            float bb0 = ld1(b2, d + 0, md), bb1 = ld1(b2, d + 1, md);
            float bb2v = ld1(b2, d + 2, md), bb3 = ld1(b2, d + 3, md);
            #pragma unroll
            for (int ii = 0; ii < 4; ++ii) {
                long long row = gbase + m0 + ty * 4 + ii;
                float o0 = acc[ii][0] + bb0, o1 = acc[ii][1] + bb1;
                float o2 = acc[ii][2] + bb2v, o3 = acc[ii][3] + bb3;
                if (md) {
                    *(float4*)((float*)out + row * DD + d) = make_float4(o0, o1, o2, o3);
                } else {
                    ushort4 o;
                    o.x = f2bf(o0); o.y = f2bf(o1); o.z = f2bf(o2); o.w = f2bf(o3);
                    *(ushort4*)((unsigned short*)out + row * DD + d) = o;
                }
            }
        }
        __syncthreads();
    }
}

// ---------------------------------------------------------------------------
extern "C" void kernel_launch(void* const* d_in, const int* in_sizes, int n_in,
                              void* d_out, int out_size, void* d_ws, size_t ws_size,
                              hipStream_t stream)
{
    const void* inp  = d_in[0];
    const void* h0   = d_in[1];
    const void* c0   = d_in[2];
    const void* wih0 = d_in[3];
    const void* whh0 = d_in[4];
    const void* bih0 = d_in[5];
    const void* bhh0 = d_in[6];
    const void* wih1 = d_in[7];
    const void* whh1 = d_in[8];
    const void* bih1 = d_in[9];
    const void* bhh1 = d_in[10];
    const void* wih2 = d_in[11];
    const void* whh2 = d_in[12];
    const void* bih2 = d_in[13];
    const void* bhh2 = d_in[14];
    const void* w1   = d_in[15];
    const void* b1   = d_in[16];
    const void* w2   = d_in[17];
    const void* b2   = d_in[18];

    int* mode = (int*)d_ws;
    float* wsf = (float*)d_ws;
    float* hstate = wsf + 16;                          // [3,256,64]
    float* cstate = hstate + 3 * BB * HH;
    float* xp  = cstate + 3 * BB * HH;                 // [TC*256, 256]
    float* hs0 = xp + (size_t)TC * BB * XP;            // [TC*256, 64]
    float* hs1 = hs0 + (size_t)TC * BB * HH;
    float* hs2 = hs1 + (size_t)TC * BB * HH;

    detect_kernel<<<1, 64, 0, stream>>>(inp, mode);
    init_state<<<192, 256, 0, stream>>>(h0, c0, hstate, cstate, mode);

    for (int c = 0; c < NC; ++c) {
        proj0_chunk<<<dim3(TC * BB / 64, 4), 256, 0, stream>>>(
            inp, wih0, bih0, bhh0, xp, mode, c);
        scan_chunk<<<BB, 256, 0, stream>>>(
            xp, hs0, whh0, hstate, cstate, mode);
        projh_chunk<<<dim3(TC * BB / 64, 4), 256, 0, stream>>>(
            hs0, wih1, bih1, bhh1, xp, mode);
        scan_chunk<<<BB, 256, 0, stream>>>(
            xp, hs1, whh1, hstate + BB * HH, cstate + BB * HH, mode);
        projh_chunk<<<dim3(TC * BB / 64, 4), 256, 0, stream>>>(
            hs1, wih2, bih2, bhh2, xp, mode);
        scan_chunk<<<BB, 256, 0, stream>>>(
            xp, hs2, whh2, hstate + 2 * BB * HH, cstate + 2 * BB * HH, mode);
        head_chunk<<<TC * BB / 64, 256, 0, stream>>>(
            hs2, w1, b1, w2, b2, d_out, mode, c);
    }
    final_state<<<192, 256, 0, stream>>>(hstate, cstate, d_out, mode);
}